// Round 6
// baseline (257.994 us; speedup 1.0000x reference)
//
#include <hip/hip_runtime.h>
#include <hip/hip_bf16.h>
#include <math.h>

// DiceLoss: B=8, C=19, H=W=512. logits fp32 [B,C,H,W], targets int [B,H,W].
// Round 6: DRAM row-locality attack. All prior rounds issued 19 x 1MB-strided
// streams at <=1 KB per row visit -> row-activate-bound ~1.9 TB/s. This round
// stages one 1024-px tile per block via global_load_lds DMA with 4 KB
// contiguous bursts per channel stream (4 back-to-back 1 KB dwordx4 DMAs),
// each wave owning whole channels. Compute runs from LDS; exp stored back.

#define CC 19
#define HWBITS 18
#define HHWW (1 << HWBITS)            // 262144
#define NPIX (8 * HHWW)               // 2,097,152
#define TP 1024                       // pixels per tile (one tile per block)
#define NBLK (NPIX / TP)              // 2048
#define NTHR 256
#define IGNORE_IDX 255

typedef const __attribute__((address_space(1))) void g_void_t;
typedef __attribute__((address_space(3))) void lds_void_t;

__device__ __forceinline__ void dma16(const void* g, void* l) {
    // lane's 16B from its own gaddr -> wave-uniform LDS base + lane*16
    __builtin_amdgcn_global_load_lds((g_void_t*)g, (lds_void_t*)l, 16, 0, 0);
}

__global__ __launch_bounds__(NTHR) void dice_accum(
    const float* __restrict__ logits,
    const int* __restrict__ targets,
    float* __restrict__ part)         // part[NBLK][64]: 0-18 S, 19-37 I, 38-56 cnt
{
    __shared__ float xs[CC * TP];     // 77824 B
    __shared__ int   ts[TP];          // 4096 B   (80 KB total -> 2 blocks/CU)

    const int tid = threadIdx.x;
    const int wave = tid >> 6;
    const int lane = tid & 63;

    const int p0 = blockIdx.x * TP;   // tile start pixel (never crosses plane)
    const int b = p0 >> HWBITS;
    const int hw0 = p0 & (HHWW - 1);

    // ---- stage: wave owns whole channels -> 4 KB contiguous burst each ----
    for (int c = wave; c < CC; c += 4) {
        const float* g = logits + (((size_t)(b * CC + c)) << HWBITS) + hw0 + lane * 4;
        float* l = &xs[c * TP];
#pragma unroll
        for (int k = 0; k < 4; ++k)          // 4 x 1 KB back-to-back = 4 KB burst
            dma16(g + k * 256, l + k * 256);
    }
    if (wave == 3) {                         // wave 3 has 4 channels; also stages targets
        const int* g = targets + p0 + lane * 4;
#pragma unroll
        for (int k = 0; k < 4; ++k)
            dma16(g + k * 256, &ts[k * 256]);
    }
    __syncthreads();                         // drains all DMA (vmcnt) + barrier

    // ---- pass 1: exp + per-pixel denominators (store exp back to LDS) ----
    const int4 tt = *(const int4*)&ts[4 * tid];
    float4 s4 = make_float4(0.f, 0.f, 0.f, 0.f);
#pragma unroll
    for (int c = 0; c < CC; ++c) {
        float4 v = *(float4*)&xs[c * TP + 4 * tid];
        v.x = __expf(v.x); v.y = __expf(v.y);
        v.z = __expf(v.z); v.w = __expf(v.w);
        *(float4*)&xs[c * TP + 4 * tid] = v;
        s4.x += v.x; s4.y += v.y; s4.z += v.z; s4.w += v.w;
    }
    const float i0 = (tt.x != IGNORE_IDX) ? __builtin_amdgcn_rcpf(s4.x) : 0.f;
    const float i1 = (tt.y != IGNORE_IDX) ? __builtin_amdgcn_rcpf(s4.y) : 0.f;
    const float i2 = (tt.z != IGNORE_IDX) ? __builtin_amdgcn_rcpf(s4.z) : 0.f;
    const float i3 = (tt.w != IGNORE_IDX) ? __builtin_amdgcn_rcpf(s4.w) : 0.f;

    // ---- pass 2: per-class accumulators (same-thread LDS, no barrier) ----
    float accS[CC], accI[CC], accC[CC];
#pragma unroll
    for (int c = 0; c < CC; ++c) {
        const float4 e = *(const float4*)&xs[c * TP + 4 * tid];
        accS[c] = fmaf(e.x, i0, fmaf(e.y, i1, fmaf(e.z, i2, e.w * i3)));
        const bool h0 = (tt.x == c), h1 = (tt.y == c);
        const bool h2 = (tt.z == c), h3 = (tt.w == c);
        accI[c] = fmaf(h0 ? e.x : 0.f, i0,
                  fmaf(h1 ? e.y : 0.f, i1,
                  fmaf(h2 ? e.z : 0.f, i2,
                       (h3 ? e.w : 0.f) * i3)));
        accC[c] = (h0 ? 1.f : 0.f) + (h1 ? 1.f : 0.f)
                + (h2 ? 1.f : 0.f) + (h3 ? 1.f : 0.f);
    }

    // ---- wave reduce, then block partials (s_part aliases xs) ----
#pragma unroll
    for (int c = 0; c < CC; ++c) {
        for (int off = 32; off; off >>= 1) {
            accS[c] += __shfl_down(accS[c], off);
            accI[c] += __shfl_down(accI[c], off);
            accC[c] += __shfl_down(accC[c], off);
        }
    }
    __syncthreads();                         // all xs reads done; safe to reuse
    float* s_part = xs;                      // [4][64]
    if (lane == 0) {
#pragma unroll
        for (int c = 0; c < CC; ++c) {
            s_part[wave * 64 + c]          = accS[c];
            s_part[wave * 64 + CC + c]     = accI[c];
            s_part[wave * 64 + 2 * CC + c] = accC[c];
        }
#pragma unroll
        for (int c = 3 * CC; c < 64; ++c) s_part[wave * 64 + c] = 0.f;
    }
    __syncthreads();
    if (tid < 64) {
        const float v = s_part[tid] + s_part[64 + tid]
                      + s_part[128 + tid] + s_part[192 + tid];
        part[blockIdx.x * 64 + tid] = v;
    }
}

__global__ __launch_bounds__(1024) void dice_final(
    const float* __restrict__ part, float* __restrict__ out)
{
    const int wave = threadIdx.x >> 6;   // 0..15
    const int lane = threadIdx.x & 63;
    float v = 0.f;
    for (int r = wave; r < NBLK; r += 16)
        v += part[r * 64 + lane];        // coalesced 256B rows

    __shared__ float s_red[16][64];
    s_red[wave][lane] = v;
    __syncthreads();

    __shared__ float s_tot[64];
    if (threadIdx.x < 64) {
        float tot = 0.f;
#pragma unroll
        for (int w = 0; w < 16; ++w) tot += s_red[w][threadIdx.x];
        s_tot[threadIdx.x] = tot;
    }
    __syncthreads();

    if (threadIdx.x == 0) {
        float loss = 0.f, totv = 0.f;
#pragma unroll
        for (int c = 0; c < CC; ++c) {
            const float S = s_tot[c];
            const float I = s_tot[CC + c];
            const float N = s_tot[2 * CC + c];
            totv += N;
            loss += 1.f - (2.f * I + 1.f) / (S + N + 1.f);
        }
        out[0] = (totv > 0.f) ? loss * (1.f / (float)CC) : 0.f;
    }
}

extern "C" void kernel_launch(void* const* d_in, const int* in_sizes, int n_in,
                              void* d_out, int out_size, void* d_ws, size_t ws_size,
                              hipStream_t stream) {
    const float* logits = (const float*)d_in[0];
    const int* targets = (const int*)d_in[1];
    float* part = (float*)d_ws;          // 2048*64*4 = 512 KB
    float* out = (float*)d_out;

    dice_accum<<<NBLK, NTHR, 0, stream>>>(logits, targets, part);
    dice_final<<<1, 1024, 0, stream>>>(part, out);
}

// Round 7
// 230.001 us; speedup vs baseline: 1.1217x; 1.1217x over previous
//
#include <hip/hip_runtime.h>
#include <hip/hip_bf16.h>
#include <math.h>

// DiceLoss: B=8, C=19, H=W=512. logits fp32 [B,C,H,W], targets int [B,H,W].
// Round 7: L1 set-conflict bypass. Identical to Round 5 (register-only hot
// loop, 19 batched float4 loads, 4 px/thread) EXCEPT all hot-loop loads are
// __builtin_nontemporal_load (nt flag -> no L1 allocation). Theory: 2^20-byte
// channel stride aliases all 19 streams into the same L1 sets; way-exhaustion
// serializes misses at ~1 line/21cy/CU = the observed 1.87 TB/s wall.

#define CC 19
#define HWBITS 18
#define HHWW (1 << HWBITS)            // 262144
#define NPIX (8 * HHWW)               // 2,097,152
#define QPP (HHWW / 4)                // 65536 float4-quads per channel plane
#define NQUAD (NPIX / 4)              // 524288
#define NBLK 1024
#define NTHR 256
#define NTH_TOT (NBLK * NTHR)         // 262144
#define NITER (NQUAD / NTH_TOT)       // 2, exact
#define IGNORE_IDX 255

typedef float f32x4 __attribute__((ext_vector_type(4)));
typedef int   i32x4 __attribute__((ext_vector_type(4)));

__global__ __launch_bounds__(NTHR, 2) void dice_accum(
    const float* __restrict__ logits,
    const int* __restrict__ targets,
    float* __restrict__ part)         // part[NBLK][64]: 0-18 S, 19-37 I, 38-56 cnt
{
    const int tid = blockIdx.x * NTHR + threadIdx.x;

    float accS[CC], accI[CC], accC[CC];
#pragma unroll
    for (int c = 0; c < CC; ++c) { accS[c] = 0.f; accI[c] = 0.f; accC[c] = 0.f; }

#pragma unroll 1                      // keep x[] live set to one iteration
    for (int it = 0; it < NITER; ++it) {
        const int q = tid + it * NTH_TOT;         // quad index
        const int b = q >> 16;                    // q / QPP
        const int hw4 = q & (QPP - 1);
        const f32x4* base = (const f32x4*)logits + (size_t)(b * CC) * QPP + hw4;

        // ---- Phase A: 19 independent nt dwordx4 loads, no L1 allocation ----
        f32x4 x[CC];
#pragma unroll
        for (int c = 0; c < CC; ++c)
            x[c] = __builtin_nontemporal_load(base + (size_t)c * QPP);
        const i32x4 tt = __builtin_nontemporal_load(
            (const i32x4*)(targets + 4 * (size_t)q));

        // ---- Phase B: exp + per-pixel denominators ----
        float s0 = 0.f, s1 = 0.f, s2 = 0.f, s3 = 0.f;
#pragma unroll
        for (int c = 0; c < CC; ++c) {
            x[c].x = __expf(x[c].x); s0 += x[c].x;
            x[c].y = __expf(x[c].y); s1 += x[c].y;
            x[c].z = __expf(x[c].z); s2 += x[c].z;
            x[c].w = __expf(x[c].w); s3 += x[c].w;
        }
        const float i0 = (tt.x != IGNORE_IDX) ? __builtin_amdgcn_rcpf(s0) : 0.f;
        const float i1 = (tt.y != IGNORE_IDX) ? __builtin_amdgcn_rcpf(s1) : 0.f;
        const float i2 = (tt.z != IGNORE_IDX) ? __builtin_amdgcn_rcpf(s2) : 0.f;
        const float i3 = (tt.w != IGNORE_IDX) ? __builtin_amdgcn_rcpf(s3) : 0.f;

        // ---- Phase C: accumulate (pure VALU) ----
#pragma unroll
        for (int c = 0; c < CC; ++c) {
            accS[c] = fmaf(x[c].x, i0,
                      fmaf(x[c].y, i1,
                      fmaf(x[c].z, i2,
                      fmaf(x[c].w, i3, accS[c]))));
            const bool h0 = (tt.x == c), h1 = (tt.y == c);
            const bool h2 = (tt.z == c), h3 = (tt.w == c);
            accI[c] = fmaf(h0 ? x[c].x : 0.f, i0,
                      fmaf(h1 ? x[c].y : 0.f, i1,
                      fmaf(h2 ? x[c].z : 0.f, i2,
                      fmaf(h3 ? x[c].w : 0.f, i3, accI[c]))));
            accC[c] += (h0 ? 1.f : 0.f) + (h1 ? 1.f : 0.f)
                     + (h2 ? 1.f : 0.f) + (h3 ? 1.f : 0.f);
        }
    }

    // ---- wave-level reduce of the 57 accumulators ----
#pragma unroll
    for (int c = 0; c < CC; ++c) {
        for (int off = 32; off; off >>= 1) {
            accS[c] += __shfl_down(accS[c], off);
            accI[c] += __shfl_down(accI[c], off);
            accC[c] += __shfl_down(accC[c], off);
        }
    }

    __shared__ float s_part[4][64];
    const int wave = threadIdx.x >> 6;
    const int lane = threadIdx.x & 63;
    if (lane == 0) {
#pragma unroll
        for (int c = 0; c < CC; ++c) {
            s_part[wave][c]          = accS[c];
            s_part[wave][CC + c]     = accI[c];
            s_part[wave][2 * CC + c] = accC[c];
        }
#pragma unroll
        for (int c = 3 * CC; c < 64; ++c) s_part[wave][c] = 0.f;  // ws is poisoned
    }
    __syncthreads();
    if (threadIdx.x < 64) {
        float v = s_part[0][threadIdx.x] + s_part[1][threadIdx.x]
                + s_part[2][threadIdx.x] + s_part[3][threadIdx.x];
        part[blockIdx.x * 64 + threadIdx.x] = v;
    }
}

__global__ __launch_bounds__(1024) void dice_final(
    const float* __restrict__ part, float* __restrict__ out)
{
    const int wave = threadIdx.x >> 6;   // 0..15
    const int lane = threadIdx.x & 63;
    float v = 0.f;
    for (int r = wave; r < NBLK; r += 16)
        v += part[r * 64 + lane];        // coalesced 256B rows

    __shared__ float s_red[16][64];
    s_red[wave][lane] = v;
    __syncthreads();

    __shared__ float s_tot[64];
    if (threadIdx.x < 64) {
        float tot = 0.f;
#pragma unroll
        for (int w = 0; w < 16; ++w) tot += s_red[w][threadIdx.x];
        s_tot[threadIdx.x] = tot;
    }
    __syncthreads();

    if (threadIdx.x == 0) {
        float loss = 0.f, totv = 0.f;
#pragma unroll
        for (int c = 0; c < CC; ++c) {
            const float S = s_tot[c];
            const float I = s_tot[CC + c];
            const float N = s_tot[2 * CC + c];
            totv += N;
            loss += 1.f - (2.f * I + 1.f) / (S + N + 1.f);
        }
        out[0] = (totv > 0.f) ? loss * (1.f / (float)CC) : 0.f;
    }
}

extern "C" void kernel_launch(void* const* d_in, const int* in_sizes, int n_in,
                              void* d_out, int out_size, void* d_ws, size_t ws_size,
                              hipStream_t stream) {
    const float* logits = (const float*)d_in[0];
    const int* targets = (const int*)d_in[1];
    float* part = (float*)d_ws;          // 1024*64*4 = 256 KB
    float* out = (float*)d_out;

    dice_accum<<<NBLK, NTHR, 0, stream>>>(logits, targets, part);
    dice_final<<<1, 1024, 0, stream>>>(part, out);
}